// Round 15
// baseline (189.886 us; speedup 1.0000x reference)
//
#include <hip/hip_runtime.h>
#include <hip/hip_bf16.h>

#define B_ 4
#define S_ 2048
#define D_ 1024
#define H_ 16
#define HD_ 64
#define M_ (B_*S_)
#define NTOK (M_*D_)

typedef __bf16 bf16;
typedef __bf16 bf16v4 __attribute__((ext_vector_type(4)));
typedef __bf16 bf16v8 __attribute__((ext_vector_type(8)));
typedef float f32x4 __attribute__((ext_vector_type(4)));
typedef float f32x16 __attribute__((ext_vector_type(16)));

#define GLDS(gp, lp) __builtin_amdgcn_global_load_lds( \
    (const __attribute__((address_space(1))) void*)(gp), \
    (__attribute__((address_space(3))) void*)(lp), 16, 0, 0)

// ---------------- prep: fused cast (data+context) + 4x weight transpose ----------------
__global__ void prep_kernel(const float* __restrict__ data, const float* __restrict__ ctx,
                            bf16* __restrict__ dataB, bf16* __restrict__ ctxB,
                            const float* __restrict__ W0, const float* __restrict__ W1,
                            const float* __restrict__ W2, const float* __restrict__ W3,
                            bf16* __restrict__ T0, bf16* __restrict__ T1,
                            bf16* __restrict__ T2, bf16* __restrict__ T3,
                            float s0) {
    int bid = blockIdx.x;
    if (bid < 8192) {
        int i = (bid * 256 + (int)threadIdx.x) * 8;
        const float* src; bf16* dst;
        if (i < NTOK) { src = data + i; dst = dataB + i; }
        else          { src = ctx + (i - NTOK); dst = ctxB + (i - NTOK); }
        const float4* p = reinterpret_cast<const float4*>(src);
        float4 x = p[0], y = p[1];
        bf16v8 o;
        o[0] = (bf16)x.x; o[1] = (bf16)x.y; o[2] = (bf16)x.z; o[3] = (bf16)x.w;
        o[4] = (bf16)y.x; o[5] = (bf16)y.y; o[6] = (bf16)y.z; o[7] = (bf16)y.w;
        *reinterpret_cast<bf16v8*>(dst) = o;
    } else {
        __shared__ float tile[32][33];
        int local = bid - 8192;
        int which = local >> 10;
        int rem = local & 1023;
        const float* W = which == 0 ? W0 : which == 1 ? W1 : which == 2 ? W2 : W3;
        bf16* Wt       = which == 0 ? T0 : which == 1 ? T1 : which == 2 ? T2 : T3;
        float scale    = which == 0 ? s0 : 1.f;
        int nb = (rem & 31) * 32, kb = (rem >> 5) * 32;
        int t = threadIdx.x;
        int c = t & 31, r0 = t >> 5;
        for (int i = 0; i < 4; ++i) {
            int r = r0 + i * 8;
            tile[r][c] = W[(size_t)(kb + r) * D_ + nb + c];
        }
        __syncthreads();
        for (int i = 0; i < 4; ++i) {
            int r = r0 + i * 8;
            Wt[(size_t)(nb + r) * D_ + kb + c] = (bf16)(tile[c][r] * scale);
        }
    }
}

// ------------- GEMM m97-structure (r11-proven): 128x128 tile, BK=64, global_load_lds, XOR swizzle -------------
// z: 0=Q(bf16), 1=K(bf16), 2=V(per-head transposed bf16), 3=O(fp32 to d_out).
__global__ __launch_bounds__(256) void gemm_qkvo_kernel(
        const bf16* __restrict__ dataB, const bf16* __restrict__ ctxB, const bf16* __restrict__ Ob,
        const bf16* __restrict__ WqT, const bf16* __restrict__ WkT,
        const bf16* __restrict__ WvT, const bf16* __restrict__ WoT,
        const float* __restrict__ bq, const float* __restrict__ bk,
        const float* __restrict__ bv, const float* __restrict__ bo,
        bf16* __restrict__ Qb, bf16* __restrict__ Kb, bf16* __restrict__ Vt,
        float* __restrict__ outp, float qscale, int zofs) {
    __shared__ bf16 Asm[128 * 64];
    __shared__ bf16 Bsm[128 * 64];
    int z = blockIdx.z + zofs;
    const bf16* A; const bf16* Bt; const float* bias; float bscale = 1.f;
    if (z == 0)      { A = dataB; Bt = WqT; bias = bq; bscale = qscale; }
    else if (z == 1) { A = ctxB;  Bt = WkT; bias = bk; }
    else if (z == 2) { A = ctxB;  Bt = WvT; bias = bv; }
    else             { A = Ob;    Bt = WoT; bias = bo; }

    int mb = blockIdx.x * 128, nb = blockIdx.y * 128;
    int t = threadIdx.x, l = t & 63, w = t >> 6;
    int wr = w >> 1, wc = w & 1;
    int lg = l >> 4, lr = l & 15;
    f32x4 acc[4][4] = {};
    int srow = t >> 3;
    int schk = t & 7;
    for (int k0 = 0; k0 < D_; k0 += 64) {
        __syncthreads();
        #pragma unroll
        for (int p = 0; p < 4; ++p) {
            int row = p * 32 + srow;
            int ca = schk ^ (row & 7);
            GLDS(&A[(size_t)(mb + row) * D_ + k0 + ca * 8], &Asm[(size_t)(p * 256 + t) * 8]);
            GLDS(&Bt[(size_t)(nb + row) * D_ + k0 + ca * 8], &Bsm[(size_t)(p * 256 + t) * 8]);
        }
        __syncthreads();
        #pragma unroll
        for (int kk = 0; kk < 2; ++kk) {
            bf16v8 af[4], bfv[4];
            #pragma unroll
            for (int i = 0; i < 4; ++i) {
                int ra = wr * 64 + i * 16 + lr;
                af[i]  = *(const bf16v8*)&Asm[ra * 64 + (((kk * 4 + lg) ^ (ra & 7)) * 8)];
                int rb = wc * 64 + i * 16 + lr;
                bfv[i] = *(const bf16v8*)&Bsm[rb * 64 + (((kk * 4 + lg) ^ (rb & 7)) * 8)];
            }
            #pragma unroll
            for (int i = 0; i < 4; ++i)
                #pragma unroll
                for (int j = 0; j < 4; ++j)
                    acc[i][j] = __builtin_amdgcn_mfma_f32_16x16x32_bf16(af[i], bfv[j], acc[i][j], 0, 0, 0);
        }
    }
    #pragma unroll
    for (int i = 0; i < 4; ++i)
        #pragma unroll
        for (int j = 0; j < 4; ++j) {
            int col = nb + wc * 64 + j * 16 + lr;
            float bvv = bias[col] * bscale;
            int row0 = mb + wr * 64 + i * 16 + lg * 4;
            if (z == 2) {
                int b = row0 >> 11, s = row0 & 2047;
                int bh = b * 16 + (col >> 6), hd = col & 63;
                bf16v4 ov;
                #pragma unroll
                for (int r = 0; r < 4; ++r) ov[r] = (bf16)(acc[i][j][r] + bvv);
                *(bf16v4*)&Vt[((size_t)bh * 64 + hd) * 2048 + s] = ov;
            } else if (z == 3) {
                #pragma unroll
                for (int r = 0; r < 4; ++r)
                    outp[(size_t)(row0 + r) * D_ + col] = acc[i][j][r] + bvv;
            } else {
                bf16* dst = (z == 0) ? Qb : Kb;
                #pragma unroll
                for (int r = 0; r < 4; ++r)
                    dst[(size_t)(row0 + r) * D_ + col] = (bf16)(acc[i][j][r] + bvv);
            }
        }
}

// ---------------- Flash attention v7: K staged in LDS; V direct global->reg (early issue) ----------------
// 4 waves x 32 q-rows (QBLK=128); no-max exp2 softmax; MFMA-ones denominator.
__global__ __launch_bounds__(256, 2) void attn_kernel(const bf16* __restrict__ Q,
                                                      const bf16* __restrict__ Kb,
                                                      const bf16* __restrict__ Vt,
                                                      bf16* __restrict__ O) {
    __shared__ bf16 Ksm[2][64 * 64];   // [buf][kv][d], 16B-chunk XOR swizzled

    int id = (int)blockIdx.x;
    int bh = id & 63;                       // id%8 = bh%8 -> head locality per XCD
    int qi = (S_ / 128 - 1) - (id >> 6);    // heavy q-blocks first
    int qb = qi * 128;
    int b = bh >> 4, h = bh & 15;
    int t = threadIdx.x, w = t >> 6, l = t & 63;
    int ln = l & 31, hi = l >> 5;
    int qwave = qb + w * 32;
    int q = qwave + ln;

    const bf16* kbase = Kb + (size_t)(b * S_) * D_ + h * HD_;
    const bf16* vbase = Vt + (size_t)bh * HD_ * S_;
    const bf16* qptr  = Q + (size_t)(b * S_ + q) * D_ + h * HD_;

    bf16v8 qf[4];
    #pragma unroll
    for (int c = 0; c < 4; ++c)
        qf[c] = *(const bf16v8*)(qptr + c * 16 + hi * 8);

    bf16v8 ones;
    #pragma unroll
    for (int e = 0; e < 8; ++e) ones[e] = (bf16)1.0f;

    f32x16 o0 = {}, o1 = {};
    f32x16 ls = {};

    int srow = t >> 3, schk = t & 7;
    int nT = 2 * qi + 2;

    auto stageK = [&](int kv0, int bufsel) {
        #pragma unroll
        for (int p = 0; p < 2; ++p) {
            int row = p * 32 + srow;
            int cs = schk ^ (row & 7);
            GLDS(kbase + (size_t)(kv0 + row) * D_ + cs * 8, &Ksm[bufsel][p * 2048 + t * 8]);
        }
    };

    stageK(0, 0);
    for (int tt = 0; tt < nT; ++tt) {
        int cur = tt & 1;
        int kv0 = tt * 64;
        __syncthreads();                    // K tile `cur` ready; prev reads done
        if (tt + 1 < nT) stageK(kv0 + 64, cur ^ 1);
        if (kv0 > qwave + 31) continue;

        // ---- V fragments: global -> reg, issued EARLY (consumed ~450 cyc later at PV) ----
        bf16v8 vf0[4], vf1[4];
        #pragma unroll
        for (int c = 0; c < 4; ++c) {
            vf0[c] = *(const bf16v8*)(vbase + (size_t)ln * S_ + kv0 + (2 * c + hi) * 8);
            vf1[c] = *(const bf16v8*)(vbase + (size_t)(32 + ln) * S_ + kv0 + (2 * c + hi) * 8);
        }

        // ---- S^T = K · Q^T ----
        f32x16 st0 = {}, st1 = {};
        __builtin_amdgcn_s_setprio(1);
        #pragma unroll
        for (int c = 0; c < 4; ++c) {
            int r0 = ln;
            bf16v8 kf0 = *(const bf16v8*)&Ksm[cur][r0 * 64 + (((2 * c + hi) ^ (r0 & 7)) * 8)];
            st0 = __builtin_amdgcn_mfma_f32_32x32x16_bf16(kf0, qf[c], st0, 0, 0, 0);
            int r1 = 32 + ln;
            bf16v8 kf1 = *(const bf16v8*)&Ksm[cur][r1 * 64 + (((2 * c + hi) ^ (r1 & 7)) * 8)];
            st1 = __builtin_amdgcn_mfma_f32_32x32x16_bf16(kf1, qf[c], st1, 0, 0, 0);
        }
        __builtin_amdgcn_s_setprio(0);

        // ---- causal mask (diagonal tiles only) ----
        if (kv0 + 63 > qwave) {
            #pragma unroll
            for (int rg = 0; rg < 16; ++rg) {
                int kvo = (rg & 3) + 8 * (rg >> 2) + 4 * hi;
                if (kv0 + kvo > q)      st0[rg] = -__builtin_inff();
                if (kv0 + 32 + kvo > q) st1[rg] = -__builtin_inff();
            }
        }

        // ---- P = exp2(S) raw (shift cancels in normalization) ----
        #pragma unroll
        for (int i = 0; i < 16; ++i) {
            st0[i] = __builtin_exp2f(st0[i]);
            st1[i] = __builtin_exp2f(st1[i]);
        }

        // ---- P -> PV B-frag: 16 cvt_pk + shfl_xor redistribution ----
        uint32_t x0[4][2], x1[4][2];
        #pragma unroll
        for (int j = 0; j < 4; ++j) {
            asm("v_cvt_pk_bf16_f32 %0, %1, %2" : "=v"(x0[j][0]) : "v"(st0[4*j+0]), "v"(st0[4*j+1]));
            asm("v_cvt_pk_bf16_f32 %0, %1, %2" : "=v"(x0[j][1]) : "v"(st0[4*j+2]), "v"(st0[4*j+3]));
            asm("v_cvt_pk_bf16_f32 %0, %1, %2" : "=v"(x1[j][0]) : "v"(st1[4*j+0]), "v"(st1[4*j+1]));
            asm("v_cvt_pk_bf16_f32 %0, %1, %2" : "=v"(x1[j][1]) : "v"(st1[4*j+2]), "v"(st1[4*j+3]));
        }
        union PB { uint32_t u[4]; bf16v8 v; };
        PB pb[4];
        #pragma unroll
        for (int c = 0; c < 4; ++c) {
            uint32_t (*xs)[2] = (c >> 1) ? x1 : x0;
            int cp = c & 1;
            #pragma unroll
            for (int d = 0; d < 2; ++d) {
                uint32_t own_lo = xs[2 * cp][d];
                uint32_t own_hi = xs[2 * cp + 1][d];
                uint32_t par_lo = __shfl_xor(own_lo, 32, 64);
                uint32_t par_hi = __shfl_xor(own_hi, 32, 64);
                pb[c].u[d]     = hi ? par_hi : own_lo;
                pb[c].u[2 + d] = hi ? own_hi : par_lo;
            }
        }

        // ---- O^T += V^T · P^T ; denominator += ones · P^T ----
        __builtin_amdgcn_s_setprio(1);
        #pragma unroll
        for (int c = 0; c < 4; ++c) {
            o0 = __builtin_amdgcn_mfma_f32_32x32x16_bf16(vf0[c], pb[c].v, o0, 0, 0, 0);
            o1 = __builtin_amdgcn_mfma_f32_32x32x16_bf16(vf1[c], pb[c].v, o1, 0, 0, 0);
            ls = __builtin_amdgcn_mfma_f32_32x32x16_bf16(ones, pb[c].v, ls, 0, 0, 0);
        }
        __builtin_amdgcn_s_setprio(0);
    }

    float li = 1.f / ls[0];
    bf16* obase = O + (size_t)(b * S_ + q) * D_ + h * HD_;
    #pragma unroll
    for (int j = 0; j < 4; ++j) {
        bf16v4 ov;
        #pragma unroll
        for (int r = 0; r < 4; ++r) ov[r] = (bf16)(o0[4 * j + r] * li);
        *(bf16v4*)(obase + 8 * j + 4 * hi) = ov;
    }
    #pragma unroll
    for (int j = 0; j < 4; ++j) {
        bf16v4 ov;
        #pragma unroll
        for (int r = 0; r < 4; ++r) ov[r] = (bf16)(o1[4 * j + r] * li);
        *(bf16v4*)(obase + 32 + 8 * j + 4 * hi) = ov;
    }
}

extern "C" void kernel_launch(void* const* d_in, const int* in_sizes, int n_in,
                              void* d_out, int out_size, void* d_ws, size_t ws_size,
                              hipStream_t stream) {
    const float* data    = (const float*)d_in[0];
    const float* context = (const float*)d_in[1];
    const float* Wq = (const float*)d_in[2];
    const float* bq = (const float*)d_in[3];
    const float* Wk = (const float*)d_in[4];
    const float* bk = (const float*)d_in[5];
    const float* Wv = (const float*)d_in[6];
    const float* bv = (const float*)d_in[7];
    const float* Wo = (const float*)d_in[8];
    const float* bo = (const float*)d_in[9];
    float* out = (float*)d_out;

    char* ws = (char*)d_ws;
    size_t off = 0;
    auto alloc = [&](size_t bytes) { void* p = ws + off; off += (bytes + 255) & ~255ull; return p; };
    bf16* dataB = (bf16*)alloc((size_t)M_ * D_ * 2);
    bf16* ctxB  = (bf16*)alloc((size_t)M_ * D_ * 2);
    bf16* WqT   = (bf16*)alloc((size_t)D_ * D_ * 2);
    bf16* WkT   = (bf16*)alloc((size_t)D_ * D_ * 2);
    bf16* WvT   = (bf16*)alloc((size_t)D_ * D_ * 2);
    bf16* WoT   = (bf16*)alloc((size_t)D_ * D_ * 2);
    bf16* Qb    = (bf16*)alloc((size_t)M_ * D_ * 2);
    bf16* Kb    = (bf16*)alloc((size_t)M_ * D_ * 2);
    bf16* Vt    = (bf16*)alloc((size_t)M_ * D_ * 2);   // [B*H][HD][S], written by V-GEMM
    bf16* Ob    = ctxB;   // ctxB dead after K/V projections

    const float qscale = 0.125f * 1.44269504088896340736f;  // 1/sqrt(64) * log2(e)

    prep_kernel<<<12288, 256, 0, stream>>>(data, context, dataB, ctxB,
                                           Wq, Wk, Wv, Wo, WqT, WkT, WvT, WoT, qscale);

    // fused Q/K/V projections (z = 0,1,2), r11-proven 128^2 structure
    gemm_qkvo_kernel<<<dim3(M_ / 128, D_ / 128, 3), 256, 0, stream>>>(
        dataB, ctxB, Ob, WqT, WkT, WvT, WoT, bq, bk, bv, bo, Qb, Kb, Vt, out, qscale, 0);

    attn_kernel<<<dim3(S_ / 128 * B_ * H_), 256, 0, stream>>>(Qb, Kb, Vt, Ob);

    // output projection (z = 3)
    gemm_qkvo_kernel<<<dim3(M_ / 128, D_ / 128, 1), 256, 0, stream>>>(
        dataB, ctxB, Ob, WqT, WkT, WvT, WoT, bq, bk, bv, bo, Qb, Kb, Vt, out, qscale, 3);
}

// Round 16
// 174.806 us; speedup vs baseline: 1.0863x; 1.0863x over previous
//
#include <hip/hip_runtime.h>
#include <hip/hip_bf16.h>

#define B_ 4
#define S_ 2048
#define D_ 1024
#define H_ 16
#define HD_ 64
#define M_ (B_*S_)
#define NTOK (M_*D_)

typedef __bf16 bf16;
typedef __bf16 bf16v4 __attribute__((ext_vector_type(4)));
typedef __bf16 bf16v8 __attribute__((ext_vector_type(8)));
typedef float f32x4 __attribute__((ext_vector_type(4)));
typedef float f32x16 __attribute__((ext_vector_type(16)));

#define GLDS(gp, lp) __builtin_amdgcn_global_load_lds( \
    (const __attribute__((address_space(1))) void*)(gp), \
    (__attribute__((address_space(3))) void*)(lp), 16, 0, 0)

// ---------------- prep: fused cast (data+context) + 4x weight transpose ----------------
__global__ void prep_kernel(const float* __restrict__ data, const float* __restrict__ ctx,
                            bf16* __restrict__ dataB, bf16* __restrict__ ctxB,
                            const float* __restrict__ W0, const float* __restrict__ W1,
                            const float* __restrict__ W2, const float* __restrict__ W3,
                            bf16* __restrict__ T0, bf16* __restrict__ T1,
                            bf16* __restrict__ T2, bf16* __restrict__ T3,
                            float s0) {
    int bid = blockIdx.x;
    if (bid < 8192) {
        int i = (bid * 256 + (int)threadIdx.x) * 8;
        const float* src; bf16* dst;
        if (i < NTOK) { src = data + i; dst = dataB + i; }
        else          { src = ctx + (i - NTOK); dst = ctxB + (i - NTOK); }
        const float4* p = reinterpret_cast<const float4*>(src);
        float4 x = p[0], y = p[1];
        bf16v8 o;
        o[0] = (bf16)x.x; o[1] = (bf16)x.y; o[2] = (bf16)x.z; o[3] = (bf16)x.w;
        o[4] = (bf16)y.x; o[5] = (bf16)y.y; o[6] = (bf16)y.z; o[7] = (bf16)y.w;
        *reinterpret_cast<bf16v8*>(dst) = o;
    } else {
        __shared__ float tile[32][33];
        int local = bid - 8192;
        int which = local >> 10;
        int rem = local & 1023;
        const float* W = which == 0 ? W0 : which == 1 ? W1 : which == 2 ? W2 : W3;
        bf16* Wt       = which == 0 ? T0 : which == 1 ? T1 : which == 2 ? T2 : T3;
        float scale    = which == 0 ? s0 : 1.f;
        int nb = (rem & 31) * 32, kb = (rem >> 5) * 32;
        int t = threadIdx.x;
        int c = t & 31, r0 = t >> 5;
        for (int i = 0; i < 4; ++i) {
            int r = r0 + i * 8;
            tile[r][c] = W[(size_t)(kb + r) * D_ + nb + c];
        }
        __syncthreads();
        for (int i = 0; i < 4; ++i) {
            int r = r0 + i * 8;
            Wt[(size_t)(nb + r) * D_ + kb + c] = (bf16)(tile[c][r] * scale);
        }
    }
}

// ------------- GEMM m97-structure: 128x128 tile, BK=64, global_load_lds, XOR swizzle -------------
// z: 0=Q(bf16), 1=K(bf16), 2=V(per-head transposed bf16), 3=O(fp32 to d_out).
__global__ __launch_bounds__(256) void gemm_qkvo_kernel(
        const bf16* __restrict__ dataB, const bf16* __restrict__ ctxB, const bf16* __restrict__ Ob,
        const bf16* __restrict__ WqT, const bf16* __restrict__ WkT,
        const bf16* __restrict__ WvT, const bf16* __restrict__ WoT,
        const float* __restrict__ bq, const float* __restrict__ bk,
        const float* __restrict__ bv, const float* __restrict__ bo,
        bf16* __restrict__ Qb, bf16* __restrict__ Kb, bf16* __restrict__ Vt,
        float* __restrict__ outp, float qscale, int zofs) {
    __shared__ bf16 Asm[128 * 64];
    __shared__ bf16 Bsm[128 * 64];
    int z = blockIdx.z + zofs;
    const bf16* A; const bf16* Bt; const float* bias; float bscale = 1.f;
    if (z == 0)      { A = dataB; Bt = WqT; bias = bq; bscale = qscale; }
    else if (z == 1) { A = ctxB;  Bt = WkT; bias = bk; }
    else if (z == 2) { A = ctxB;  Bt = WvT; bias = bv; }
    else             { A = Ob;    Bt = WoT; bias = bo; }

    int mb = blockIdx.x * 128, nb = blockIdx.y * 128;
    int t = threadIdx.x, l = t & 63, w = t >> 6;
    int wr = w >> 1, wc = w & 1;
    int lg = l >> 4, lr = l & 15;
    f32x4 acc[4][4] = {};
    int srow = t >> 3;
    int schk = t & 7;
    for (int k0 = 0; k0 < D_; k0 += 64) {
        __syncthreads();
        #pragma unroll
        for (int p = 0; p < 4; ++p) {
            int row = p * 32 + srow;
            int ca = schk ^ (row & 7);
            GLDS(&A[(size_t)(mb + row) * D_ + k0 + ca * 8], &Asm[(size_t)(p * 256 + t) * 8]);
            GLDS(&Bt[(size_t)(nb + row) * D_ + k0 + ca * 8], &Bsm[(size_t)(p * 256 + t) * 8]);
        }
        __syncthreads();
        #pragma unroll
        for (int kk = 0; kk < 2; ++kk) {
            bf16v8 af[4], bfv[4];
            #pragma unroll
            for (int i = 0; i < 4; ++i) {
                int ra = wr * 64 + i * 16 + lr;
                af[i]  = *(const bf16v8*)&Asm[ra * 64 + (((kk * 4 + lg) ^ (ra & 7)) * 8)];
                int rb = wc * 64 + i * 16 + lr;
                bfv[i] = *(const bf16v8*)&Bsm[rb * 64 + (((kk * 4 + lg) ^ (rb & 7)) * 8)];
            }
            #pragma unroll
            for (int i = 0; i < 4; ++i)
                #pragma unroll
                for (int j = 0; j < 4; ++j)
                    acc[i][j] = __builtin_amdgcn_mfma_f32_16x16x32_bf16(af[i], bfv[j], acc[i][j], 0, 0, 0);
        }
    }
    #pragma unroll
    for (int i = 0; i < 4; ++i)
        #pragma unroll
        for (int j = 0; j < 4; ++j) {
            int col = nb + wc * 64 + j * 16 + lr;
            float bvv = bias[col] * bscale;
            int row0 = mb + wr * 64 + i * 16 + lg * 4;
            if (z == 2) {
                // V: per-head transposed write Vt[bh][hd][s], 4 consecutive s -> 8B store
                int b = row0 >> 11, s = row0 & 2047;
                int bh = b * 16 + (col >> 6), hd = col & 63;
                bf16v4 ov;
                #pragma unroll
                for (int r = 0; r < 4; ++r) ov[r] = (bf16)(acc[i][j][r] + bvv);
                *(bf16v4*)&Vt[((size_t)bh * 64 + hd) * 2048 + s] = ov;
            } else if (z == 3) {
                #pragma unroll
                for (int r = 0; r < 4; ++r)
                    outp[(size_t)(row0 + r) * D_ + col] = acc[i][j][r] + bvv;
            } else {
                bf16* dst = (z == 0) ? Qb : Kb;
                #pragma unroll
                for (int r = 0; r < 4; ++r)
                    dst[(size_t)(row0 + r) * D_ + col] = (bf16)(acc[i][j][r] + bvv);
            }
        }
}

// ---------------- Flash attention v6 (r11 config): no-max softmax, MFMA denominator ----------------
__global__ __launch_bounds__(256, 2) void attn_kernel(const bf16* __restrict__ Q,
                                                      const bf16* __restrict__ Kb,
                                                      const bf16* __restrict__ Vt,
                                                      bf16* __restrict__ O) {
    __shared__ bf16 Ksm[2][64 * 64];   // [buf][kv][d], 16B-chunk XOR swizzled
    __shared__ bf16 Vsm[2][64 * 64];   // [buf][d][kv], 16B-chunk XOR swizzled

    int id = (int)blockIdx.x;
    int bh = id & 63;                       // id%8 = bh%8 -> head locality per XCD
    int qi = (S_ / 128 - 1) - (id >> 6);    // heavy q-blocks first
    int qb = qi * 128;
    int b = bh >> 4, h = bh & 15;
    int t = threadIdx.x, w = t >> 6, l = t & 63;
    int ln = l & 31, hi = l >> 5;
    int qwave = qb + w * 32;
    int q = qwave + ln;

    const bf16* kbase = Kb + (size_t)(b * S_) * D_ + h * HD_;
    const bf16* vbase = Vt + (size_t)bh * HD_ * S_;
    const bf16* qptr  = Q + (size_t)(b * S_ + q) * D_ + h * HD_;

    bf16v8 qf[4];
    #pragma unroll
    for (int c = 0; c < 4; ++c)
        qf[c] = *(const bf16v8*)(qptr + c * 16 + hi * 8);

    bf16v8 ones;
    #pragma unroll
    for (int e = 0; e < 8; ++e) ones[e] = (bf16)1.0f;

    f32x16 o0 = {}, o1 = {};
    f32x16 ls = {};

    int srow = t >> 3, schk = t & 7;
    int nT = 2 * qi + 2;

    auto stage = [&](int kv0, int bufsel) {
        #pragma unroll
        for (int p = 0; p < 2; ++p) {
            int row = p * 32 + srow;
            int cs = schk ^ (row & 7);
            GLDS(kbase + (size_t)(kv0 + row) * D_ + cs * 8, &Ksm[bufsel][p * 2048 + t * 8]);
            GLDS(vbase + (size_t)row * S_ + kv0 + cs * 8,   &Vsm[bufsel][p * 2048 + t * 8]);
        }
    };

    stage(0, 0);
    for (int tt = 0; tt < nT; ++tt) {
        int cur = tt & 1;
        int kv0 = tt * 64;
        __syncthreads();
        if (tt + 1 < nT) stage(kv0 + 64, cur ^ 1);
        if (kv0 > qwave + 31) continue;

        f32x16 st0 = {}, st1 = {};
        __builtin_amdgcn_s_setprio(1);
        #pragma unroll
        for (int c = 0; c < 4; ++c) {
            int r0 = ln;
            bf16v8 kf0 = *(const bf16v8*)&Ksm[cur][r0 * 64 + (((2 * c + hi) ^ (r0 & 7)) * 8)];
            st0 = __builtin_amdgcn_mfma_f32_32x32x16_bf16(kf0, qf[c], st0, 0, 0, 0);
            int r1 = 32 + ln;
            bf16v8 kf1 = *(const bf16v8*)&Ksm[cur][r1 * 64 + (((2 * c + hi) ^ (r1 & 7)) * 8)];
            st1 = __builtin_amdgcn_mfma_f32_32x32x16_bf16(kf1, qf[c], st1, 0, 0, 0);
        }
        __builtin_amdgcn_s_setprio(0);

        if (kv0 + 63 > qwave) {
            #pragma unroll
            for (int rg = 0; rg < 16; ++rg) {
                int kvo = (rg & 3) + 8 * (rg >> 2) + 4 * hi;
                if (kv0 + kvo > q)      st0[rg] = -__builtin_inff();
                if (kv0 + 32 + kvo > q) st1[rg] = -__builtin_inff();
            }
        }

        #pragma unroll
        for (int i = 0; i < 16; ++i) {
            st0[i] = __builtin_exp2f(st0[i]);
            st1[i] = __builtin_exp2f(st1[i]);
        }

        uint32_t x0[4][2], x1[4][2];
        #pragma unroll
        for (int j = 0; j < 4; ++j) {
            asm("v_cvt_pk_bf16_f32 %0, %1, %2" : "=v"(x0[j][0]) : "v"(st0[4*j+0]), "v"(st0[4*j+1]));
            asm("v_cvt_pk_bf16_f32 %0, %1, %2" : "=v"(x0[j][1]) : "v"(st0[4*j+2]), "v"(st0[4*j+3]));
            asm("v_cvt_pk_bf16_f32 %0, %1, %2" : "=v"(x1[j][0]) : "v"(st1[4*j+0]), "v"(st1[4*j+1]));
            asm("v_cvt_pk_bf16_f32 %0, %1, %2" : "=v"(x1[j][1]) : "v"(st1[4*j+2]), "v"(st1[4*j+3]));
        }
        union PB { uint32_t u[4]; bf16v8 v; };
        PB pb[4];
        #pragma unroll
        for (int c = 0; c < 4; ++c) {
            uint32_t (*xs)[2] = (c >> 1) ? x1 : x0;
            int cp = c & 1;
            #pragma unroll
            for (int d = 0; d < 2; ++d) {
                uint32_t own_lo = xs[2 * cp][d];
                uint32_t own_hi = xs[2 * cp + 1][d];
                uint32_t par_lo = __shfl_xor(own_lo, 32, 64);
                uint32_t par_hi = __shfl_xor(own_hi, 32, 64);
                pb[c].u[d]     = hi ? par_hi : own_lo;
                pb[c].u[2 + d] = hi ? own_hi : par_lo;
            }
        }

        __builtin_amdgcn_s_setprio(1);
        #pragma unroll
        for (int c = 0; c < 4; ++c) {
            int r0 = ln;
            bf16v8 va0 = *(const bf16v8*)&Vsm[cur][r0 * 64 + (((2 * c + hi) ^ (r0 & 7)) * 8)];
            o0 = __builtin_amdgcn_mfma_f32_32x32x16_bf16(va0, pb[c].v, o0, 0, 0, 0);
            int r1 = 32 + ln;
            bf16v8 va1 = *(const bf16v8*)&Vsm[cur][r1 * 64 + (((2 * c + hi) ^ (r1 & 7)) * 8)];
            o1 = __builtin_amdgcn_mfma_f32_32x32x16_bf16(va1, pb[c].v, o1, 0, 0, 0);
            ls = __builtin_amdgcn_mfma_f32_32x32x16_bf16(ones, pb[c].v, ls, 0, 0, 0);
        }
        __builtin_amdgcn_s_setprio(0);
    }

    float li = 1.f / ls[0];
    bf16* obase = O + (size_t)(b * S_ + q) * D_ + h * HD_;
    #pragma unroll
    for (int j = 0; j < 4; ++j) {
        bf16v4 ov;
        #pragma unroll
        for (int r = 0; r < 4; ++r) ov[r] = (bf16)(o0[4 * j + r] * li);
        *(bf16v4*)(obase + 8 * j + 4 * hi) = ov;
    }
    #pragma unroll
    for (int j = 0; j < 4; ++j) {
        bf16v4 ov;
        #pragma unroll
        for (int r = 0; r < 4; ++r) ov[r] = (bf16)(o1[4 * j + r] * li);
        *(bf16v4*)(obase + 32 + 8 * j + 4 * hi) = ov;
    }
}

extern "C" void kernel_launch(void* const* d_in, const int* in_sizes, int n_in,
                              void* d_out, int out_size, void* d_ws, size_t ws_size,
                              hipStream_t stream) {
    const float* data    = (const float*)d_in[0];
    const float* context = (const float*)d_in[1];
    const float* Wq = (const float*)d_in[2];
    const float* bq = (const float*)d_in[3];
    const float* Wk = (const float*)d_in[4];
    const float* bk = (const float*)d_in[5];
    const float* Wv = (const float*)d_in[6];
    const float* bv = (const float*)d_in[7];
    const float* Wo = (const float*)d_in[8];
    const float* bo = (const float*)d_in[9];
    float* out = (float*)d_out;

    char* ws = (char*)d_ws;
    size_t off = 0;
    auto alloc = [&](size_t bytes) { void* p = ws + off; off += (bytes + 255) & ~255ull; return p; };
    bf16* dataB = (bf16*)alloc((size_t)M_ * D_ * 2);
    bf16* ctxB  = (bf16*)alloc((size_t)M_ * D_ * 2);
    bf16* WqT   = (bf16*)alloc((size_t)D_ * D_ * 2);
    bf16* WkT   = (bf16*)alloc((size_t)D_ * D_ * 2);
    bf16* WvT   = (bf16*)alloc((size_t)D_ * D_ * 2);
    bf16* WoT   = (bf16*)alloc((size_t)D_ * D_ * 2);
    bf16* Qb    = (bf16*)alloc((size_t)M_ * D_ * 2);
    bf16* Kb    = (bf16*)alloc((size_t)M_ * D_ * 2);
    bf16* Vt    = (bf16*)alloc((size_t)M_ * D_ * 2);   // [B*H][HD][S], written by V-GEMM
    bf16* Ob    = ctxB;   // ctxB dead after K/V projections

    const float qscale = 0.125f * 1.44269504088896340736f;  // 1/sqrt(64) * log2(e)

    prep_kernel<<<12288, 256, 0, stream>>>(data, context, dataB, ctxB,
                                           Wq, Wk, Wv, Wo, WqT, WkT, WvT, WoT, qscale);

    // fused Q/K/V projections (z = 0,1,2)
    gemm_qkvo_kernel<<<dim3(M_ / 128, D_ / 128, 3), 256, 0, stream>>>(
        dataB, ctxB, Ob, WqT, WkT, WvT, WoT, bq, bk, bv, bo, Qb, Kb, Vt, out, qscale, 0);

    attn_kernel<<<dim3(S_ / 128 * B_ * H_), 256, 0, stream>>>(Qb, Kb, Vt, Ob);

    // output projection (z = 3)
    gemm_qkvo_kernel<<<dim3(M_ / 128, D_ / 128, 1), 256, 0, stream>>>(
        dataB, ctxB, Ob, WqT, WkT, WvT, WoT, bq, bk, bv, bo, Qb, Kb, Vt, out, qscale, 3);
}